// Round 2
// baseline (538.378 us; speedup 1.0000x reference)
//
#include <hip/hip_runtime.h>

// GCN 2-layer: x[N,4] @ W1[4,16] -> gather/scatter normalize -> relu -> @W2[16,1] -> gather/scatter
// N = 200000, E = 3200000. Scatter-add via fp32 atomics (L2-resident accumulators).

__global__ void k_degree(const int* __restrict__ dst, int E, int* __restrict__ deg) {
    int i = blockIdx.x * blockDim.x + threadIdx.x;
    if (i < E) atomicAdd(&deg[dst[i]], 1);
}

// Per node: dinv, h = x@W1, h_scaled = h*dinv. acc1 zeroed here too.
__global__ void k_node1(const float* __restrict__ x, const int* __restrict__ deg,
                        const float* __restrict__ W1, const float* __restrict__ b1,
                        float* __restrict__ dinv, float* __restrict__ h_scaled,
                        float* __restrict__ acc1, int N) {
    int i = blockIdx.x * blockDim.x + threadIdx.x;
    if (i >= N) return;
    // self-loop adds 1 to the dst-degree histogram
    float d = (float)(deg[i] + 1);
    float di = 1.0f / sqrtf(d);
    dinv[i] = di;
    float4 xv = ((const float4*)x)[i];
    #pragma unroll
    for (int c = 0; c < 16; ++c) {
        float h = xv.x * W1[0 * 16 + c] + xv.y * W1[1 * 16 + c]
                + xv.z * W1[2 * 16 + c] + xv.w * W1[3 * 16 + c];
        h_scaled[i * 16 + c] = h * di;   // pre-scale by dinv[src]
        acc1[i * 16 + c] = 0.0f;         // edge-sum accumulator
    }
}

// 16 threads per edge: acc1[dst][j] += h_scaled[src][j]  (dinv[dst] applied later)
__global__ void k_scatter1(const int* __restrict__ src, const int* __restrict__ dst,
                           const float* __restrict__ h_scaled,
                           float* __restrict__ acc1, long long T) {
    long long t = (long long)blockIdx.x * blockDim.x + threadIdx.x;
    if (t >= T) return;
    int e = (int)(t >> 4);
    int j = (int)(t & 15);
    int s = src[e];
    int d = dst[e];
    atomicAdd(&acc1[(long long)d * 16 + j], h_scaled[(long long)s * 16 + j]);
}

// Per node: h1 = relu(di*(acc1 + h_scaled) + b1); z = h1@W2;
// z_scaled = z*di; out = self-loop + bias (edge atomics added by k_scatter2).
// Note: self-loop term inside the di*(...) scale is h_scaled = h*di, giving
// the correct h*di^2 — NOT h_scaled*di (that was the round-1 bug: h*di^3).
__global__ void k_node2(const float* __restrict__ acc1, const float* __restrict__ h_scaled,
                        const float* __restrict__ dinv,
                        const float* __restrict__ b1, const float* __restrict__ W2,
                        const float* __restrict__ b2,
                        float* __restrict__ z_scaled, float* __restrict__ out, int N) {
    int i = blockIdx.x * blockDim.x + threadIdx.x;
    if (i >= N) return;
    float di = dinv[i];
    float z = 0.0f;
    #pragma unroll
    for (int c = 0; c < 16; ++c) {
        float sum = acc1[i * 16 + c] + h_scaled[i * 16 + c]; // edges + self-loop (pre dst-scale)
        float h1 = di * sum + b1[c];
        h1 = fmaxf(h1, 0.0f);
        z += h1 * W2[c];
    }
    float zsv = z * di;
    z_scaled[i] = zsv;
    out[i] = zsv * di + b2[0];   // self-loop term z*di^2 + bias; edges via atomics next
}

// 1 thread per edge: out[dst] += z_scaled[src] * dinv[dst]
__global__ void k_scatter2(const int* __restrict__ src, const int* __restrict__ dst,
                           const float* __restrict__ dinv, const float* __restrict__ z_scaled,
                           float* __restrict__ out, int E) {
    int e = blockIdx.x * blockDim.x + threadIdx.x;
    if (e < E) {
        int d = dst[e];
        atomicAdd(&out[d], z_scaled[src[e]] * dinv[d]);
    }
}

extern "C" void kernel_launch(void* const* d_in, const int* in_sizes, int n_in,
                              void* d_out, int out_size, void* d_ws, size_t ws_size,
                              hipStream_t stream) {
    const float* x  = (const float*)d_in[0];
    const int*   ei = (const int*)d_in[1];   // [2, E] int32 per harness convention
    const float* W1 = (const float*)d_in[2];
    const float* b1 = (const float*)d_in[3];
    const float* W2 = (const float*)d_in[4];
    const float* b2 = (const float*)d_in[5];

    const int N = in_sizes[0] / 4;
    const int E = in_sizes[1] / 2;
    const int* src = ei;
    const int* dst = ei + E;

    // Workspace layout (all 4-byte types):
    //   deg[N] (int) | dinv[N] | z_scaled[N] | h_scaled[N*16] | acc1[N*16]
    char* ws = (char*)d_ws;
    int*   deg      = (int*)ws;    ws += (size_t)N * 4;
    float* dinv     = (float*)ws;  ws += (size_t)N * 4;
    float* z_scaled = (float*)ws;  ws += (size_t)N * 4;
    float* h_scaled = (float*)ws;  ws += (size_t)N * 16 * 4;
    float* acc1     = (float*)ws;  ws += (size_t)N * 16 * 4;
    float* out = (float*)d_out;

    const int B = 256;

    hipMemsetAsync(deg, 0, (size_t)N * sizeof(int), stream);
    k_degree<<<(E + B - 1) / B, B, 0, stream>>>(dst, E, deg);
    k_node1<<<(N + B - 1) / B, B, 0, stream>>>(x, deg, W1, b1, dinv, h_scaled, acc1, N);
    long long T = (long long)E * 16;
    k_scatter1<<<(int)((T + B - 1) / B), B, 0, stream>>>(src, dst, h_scaled, acc1, T);
    k_node2<<<(N + B - 1) / B, B, 0, stream>>>(acc1, h_scaled, dinv, b1, W2, b2,
                                               z_scaled, out, N);
    k_scatter2<<<(E + B - 1) / B, B, 0, stream>>>(src, dst, dinv, z_scaled, out, E);
}

// Round 3
// 524.647 us; speedup vs baseline: 1.0262x; 1.0262x over previous
//
#include <hip/hip_runtime.h>

// GCN 2-layer, N=200000, E=3200000.
// Key trick: segment_sum((x@W1)[src]*norm) == segment_sum(x_scaled[src]) @ W1
// (linearity) -> aggregate the 4-dim x*dinv instead of the 16-dim h*dinv.
// 4 atomics/edge instead of 16, and the gathered array (x_scaled, 3.2 MB)
// fits in per-XCD L2.

__global__ void k_degree(const int* __restrict__ dst, int E, int* __restrict__ deg) {
    int i = blockIdx.x * blockDim.x + threadIdx.x;
    if (i < E) atomicAdd(&deg[dst[i]], 1);
}

// Per node: dinv, x_scaled = x*dinv (float4), zero acc4.
__global__ void k_node1(const float* __restrict__ x, const int* __restrict__ deg,
                        float* __restrict__ dinv, float* __restrict__ x_scaled,
                        float* __restrict__ acc4, int N) {
    int i = blockIdx.x * blockDim.x + threadIdx.x;
    if (i >= N) return;
    float d = (float)(deg[i] + 1);           // +1: self loop
    float di = 1.0f / sqrtf(d);
    dinv[i] = di;
    float4 xv = ((const float4*)x)[i];
    float4 xs = make_float4(xv.x * di, xv.y * di, xv.z * di, xv.w * di);
    ((float4*)x_scaled)[i] = xs;
    ((float4*)acc4)[i] = make_float4(0.f, 0.f, 0.f, 0.f);
}

// 4 lanes per edge: acc4[dst][j] += x_scaled[src][j]
__global__ void k_scatter1(const int* __restrict__ src, const int* __restrict__ dst,
                           const float* __restrict__ x_scaled,
                           float* __restrict__ acc4, long long T) {
    long long t = (long long)blockIdx.x * blockDim.x + threadIdx.x;
    if (t >= T) return;
    int e = (int)(t >> 2);
    int j = (int)(t & 3);
    int s = src[e];
    int d = dst[e];
    atomicAdd(&acc4[d * 4 + j], x_scaled[s * 4 + j]);
}

// Per node: agg = acc4 + x_scaled (self loop); pre = di*agg;
// h1 = relu(pre@W1 + b1); z = h1@W2; z_scaled = z*di; out = z*di^2 + b2.
__global__ void k_node2(const float* __restrict__ acc4, const float* __restrict__ x_scaled,
                        const float* __restrict__ dinv,
                        const float* __restrict__ W1, const float* __restrict__ b1,
                        const float* __restrict__ W2, const float* __restrict__ b2,
                        float* __restrict__ z_scaled, float* __restrict__ out, int N) {
    int i = blockIdx.x * blockDim.x + threadIdx.x;
    if (i >= N) return;
    float di = dinv[i];
    float4 a = ((const float4*)acc4)[i];
    float4 xs = ((const float4*)x_scaled)[i];
    float p0 = di * (a.x + xs.x);
    float p1 = di * (a.y + xs.y);
    float p2 = di * (a.z + xs.z);
    float p3 = di * (a.w + xs.w);
    float z = 0.0f;
    #pragma unroll
    for (int c = 0; c < 16; ++c) {
        float h1 = p0 * W1[0 * 16 + c] + p1 * W1[1 * 16 + c]
                 + p2 * W1[2 * 16 + c] + p3 * W1[3 * 16 + c] + b1[c];
        h1 = fmaxf(h1, 0.0f);
        z += h1 * W2[c];
    }
    float zsv = z * di;
    z_scaled[i] = zsv;
    out[i] = zsv * di + b2[0];   // self-loop term + bias; edge atomics next
}

// 1 thread per edge: out[dst] += z_scaled[src] * dinv[dst]
__global__ void k_scatter2(const int* __restrict__ src, const int* __restrict__ dst,
                           const float* __restrict__ dinv, const float* __restrict__ z_scaled,
                           float* __restrict__ out, int E) {
    int e = blockIdx.x * blockDim.x + threadIdx.x;
    if (e < E) {
        int d = dst[e];
        atomicAdd(&out[d], z_scaled[src[e]] * dinv[d]);
    }
}

extern "C" void kernel_launch(void* const* d_in, const int* in_sizes, int n_in,
                              void* d_out, int out_size, void* d_ws, size_t ws_size,
                              hipStream_t stream) {
    const float* x  = (const float*)d_in[0];
    const int*   ei = (const int*)d_in[1];   // [2, E] as int32
    const float* W1 = (const float*)d_in[2];
    const float* b1 = (const float*)d_in[3];
    const float* W2 = (const float*)d_in[4];
    const float* b2 = (const float*)d_in[5];

    const int N = in_sizes[0] / 4;
    const int E = in_sizes[1] / 2;
    const int* src = ei;
    const int* dst = ei + E;

    // Workspace: deg[N] int | dinv[N] | z_scaled[N] | x_scaled[N*4] | acc4[N*4]
    char* ws = (char*)d_ws;
    int*   deg      = (int*)ws;    ws += (size_t)N * 4;
    float* dinv     = (float*)ws;  ws += (size_t)N * 4;
    float* z_scaled = (float*)ws;  ws += (size_t)N * 4;
    float* x_scaled = (float*)ws;  ws += (size_t)N * 4 * 4;
    float* acc4     = (float*)ws;  ws += (size_t)N * 4 * 4;
    float* out = (float*)d_out;

    const int B = 256;

    hipMemsetAsync(deg, 0, (size_t)N * sizeof(int), stream);
    k_degree<<<(E + B - 1) / B, B, 0, stream>>>(dst, E, deg);
    k_node1<<<(N + B - 1) / B, B, 0, stream>>>(x, deg, dinv, x_scaled, acc4, N);
    long long T = (long long)E * 4;
    k_scatter1<<<(int)((T + B - 1) / B), B, 0, stream>>>(src, dst, x_scaled, acc4, T);
    k_node2<<<(N + B - 1) / B, B, 0, stream>>>(acc4, x_scaled, dinv, W1, b1, W2, b2,
                                               z_scaled, out, N);
    k_scatter2<<<(E + B - 1) / B, B, 0, stream>>>(src, dst, dinv, z_scaled, out, E);
}